// Round 8
// baseline (46.902 us; speedup 1.0000x reference)
//
#include <hip/hip_runtime.h>

#define HH 14
#define WW 14
#define P 196          // HH*WW
#define SENT 196
#define CTOT 2048
#define NCHUNK 16
#define CCHUNK 128     // CTOT/NCHUNK
#define Q4 49          // P/4 float4 per channel row

// DIAGNOSTIC ROUND: identical R6 kernels; chansum launched TWICE (second run
// overwrites identical values -> output unchanged, deterministic). The dur_us
// delta vs R6 (31.6) measures T_chansum directly, splitting the 31.6 into
// chansum vs (bbox + graph overhead) to steer the final optimization.

// ---------------- kernel 1: partial channel sums (round-1 exact) ----------------
__global__ __launch_bounds__(256) void chansum_kernel(const float* __restrict__ fms,
                                                      float* __restrict__ partials) {
    const int blk = blockIdx.x;
    const int b = blk >> 4;       // /NCHUNK
    const int k = blk & 15;       // %NCHUNK
    const float4* __restrict__ base =
        (const float4*)(fms + ((size_t)b * CTOT + (size_t)k * CCHUNK) * P);

    __shared__ float lds[5 * P];
    const int t = threadIdx.x;

    if (t < 5 * Q4) {             // 245 active lanes
        const int q = t % Q4;     // float4 column within a channel row
        const int r = t / Q4;     // row-group 0..4
        float4 acc = {0.f, 0.f, 0.f, 0.f};
        #pragma unroll 4
        for (int c = r; c < CCHUNK; c += 5) {
            float4 v = base[c * Q4 + q];
            acc.x += v.x; acc.y += v.y; acc.z += v.z; acc.w += v.w;
        }
        const int o = r * P + q * 4;
        lds[o + 0] = acc.x; lds[o + 1] = acc.y;
        lds[o + 2] = acc.z; lds[o + 3] = acc.w;
    }
    __syncthreads();
    if (t < P) {
        float s = lds[t] + lds[P + t] + lds[2 * P + t] + lds[3 * P + t] + lds[4 * P + t];
        partials[(size_t)blk * P + t] = s;
    }
}

// ---------------- kernel 2: threshold + CC + bbox (R6 exact) ----------------
__global__ __launch_bounds__(256) void bbox_kernel(const float* __restrict__ partials,
                                                   int* __restrict__ out) {
    const int b = blockIdx.x;
    const int t = threadIdx.x;

    __shared__ int labA[P], labB[P];
    __shared__ int cnt[P];
    __shared__ float redf[4];
    __shared__ int redi[4];
    __shared__ int wr[4][4];

    float a = -1e30f;
    if (t < P) {
        const float* pb = partials + (size_t)b * NCHUNK * P + t;
        a = 0.f;
        #pragma unroll
        for (int k = 0; k < NCHUNK; ++k) a += pb[k * P];
    }

    float mx = a;
    #pragma unroll
    for (int off = 32; off >= 1; off >>= 1) mx = fmaxf(mx, __shfl_xor(mx, off));
    if ((t & 63) == 0) redf[t >> 6] = mx;
    __syncthreads();
    const float maxv = fmaxf(fmaxf(redf[0], redf[1]), fmaxf(redf[2], redf[3]));
    const float thr = maxv * 0.3f;

    const bool maskp = (t < P) && (a > thr);
    const int row = t / WW;
    const int col = t % WW;
    int cur = maskp ? t : SENT;
    if (t < P) labA[t] = cur;
    __syncthreads();

    int pp = 0;
    for (;;) {
        const int* __restrict__ src = pp ? labB : labA;
        int* __restrict__ dst = pp ? labA : labB;
        int m2 = SENT;
        if (maskp) {
            m2 = cur;
            #pragma unroll
            for (int dr = -1; dr <= 1; ++dr) {
                const int rr = row + dr;
                if (rr < 0 || rr >= HH) continue;
                #pragma unroll
                for (int dc = -1; dc <= 1; ++dc) {
                    const int cc = col + dc;
                    if (cc < 0 || cc >= WW) continue;
                    m2 = min(m2, src[rr * WW + cc]);
                }
            }
        }
        if (t < P) dst[t] = m2;
        const int changed = (m2 != cur);
        cur = m2;
        pp ^= 1;
        if (!__syncthreads_or(changed)) break;
    }

    if (t < P) cnt[t] = 0;
    __syncthreads();
    if (maskp) atomicAdd(&cnt[cur], 1);
    __syncthreads();

    int key = (t < P) ? (cnt[t] * 256 + (255 - t)) : 0;
    #pragma unroll
    for (int off = 32; off >= 1; off >>= 1) key = max(key, __shfl_xor(key, off));
    if ((t & 63) == 0) redi[t >> 6] = key;
    __syncthreads();
    const int bkey = max(max(redi[0], redi[1]), max(redi[2], redi[3]));
    const int best = 255 - (bkey & 255);
    const int bcnt = bkey >> 8;

    int mnr = HH, mxr = -1, mnc = WW, mxc = -1;
    if (maskp && bcnt > 0 && cur == best) { mnr = row; mxr = row; mnc = col; mxc = col; }
    #pragma unroll
    for (int off = 32; off >= 1; off >>= 1) {
        mnr = min(mnr, __shfl_xor(mnr, off));
        mxr = max(mxr, __shfl_xor(mxr, off));
        mnc = min(mnc, __shfl_xor(mnc, off));
        mxc = max(mxc, __shfl_xor(mxc, off));
    }
    const int wid = t >> 6;
    if ((t & 63) == 0) { wr[0][wid] = mnr; wr[1][wid] = mxr; wr[2][wid] = mnc; wr[3][wid] = mxc; }
    __syncthreads();

    if (t == 0) {
        #pragma unroll
        for (int w = 1; w < 4; ++w) {
            mnr = min(mnr, wr[0][w]); mxr = max(mxr, wr[1][w]);
            mnc = min(mnc, wr[2][w]); mxc = max(mxc, wr[3][w]);
        }
        if (bcnt == 0) { mnr = 0; mxr = HH - 1; mnc = 0; mxc = WW - 1; }
        out[b * 4 + 0] = max(mnr * 32 - 1, 0);
        out[b * 4 + 1] = max(mnc * 32 - 1, 0);
        out[b * 4 + 2] = (mxr + 1) * 32 - 1;
        out[b * 4 + 3] = (mxc + 1) * 32 - 1;
    }
}

extern "C" void kernel_launch(void* const* d_in, const int* in_sizes, int n_in,
                              void* d_out, int out_size, void* d_ws, size_t ws_size,
                              hipStream_t stream) {
    const float* fms = (const float*)d_in[0];
    int* out = (int*)d_out;
    float* partials = (float*)d_ws;   // 64*NCHUNK*196 floats = 802,816 B

    // chansum launched TWICE (diagnostic: dur delta vs R6 == T_chansum).
    chansum_kernel<<<dim3(64 * NCHUNK), dim3(256), 0, stream>>>(fms, partials);
    chansum_kernel<<<dim3(64 * NCHUNK), dim3(256), 0, stream>>>(fms, partials);
    bbox_kernel<<<dim3(64), dim3(256), 0, stream>>>(partials, out);
}

// Round 9
// 26.545 us; speedup vs baseline: 1.7669x; 1.7669x over previous
//
#include <hip/hip_runtime.h>

#define HH 14
#define WW 14
#define P 196          // HH*WW
#define CTOT 2048
#define NCHUNK 16
#define CCHUNK 128     // CTOT/NCHUNK
#define Q4 49          // P/4 float4 per channel row

// ---------------- kernel 1: partial channel sums (R1/R6 exact) ----------------
// grid = 64*NCHUNK = 1024 blocks, 256 threads. Block (b,k) sums channels
// [k*CCHUNK,(k+1)*CCHUNK) into partials[b*16+k][196]. Measured ~15 us (R8
// double-launch diagnostic) ~= LLC/HBM stream floor.
__global__ __launch_bounds__(256) void chansum_kernel(const float* __restrict__ fms,
                                                      float* __restrict__ partials) {
    const int blk = blockIdx.x;
    const int b = blk >> 4;       // /NCHUNK
    const int k = blk & 15;       // %NCHUNK
    const float4* __restrict__ base =
        (const float4*)(fms + ((size_t)b * CTOT + (size_t)k * CCHUNK) * P);

    __shared__ float lds[5 * P];
    const int t = threadIdx.x;

    if (t < 5 * Q4) {             // 245 active lanes
        const int q = t % Q4;     // float4 column within a channel row
        const int r = t / Q4;     // row-group 0..4
        float4 acc = {0.f, 0.f, 0.f, 0.f};
        #pragma unroll 4
        for (int c = r; c < CCHUNK; c += 5) {
            float4 v = base[c * Q4 + q];
            acc.x += v.x; acc.y += v.y; acc.z += v.z; acc.w += v.w;
        }
        const int o = r * P + q * 4;
        lds[o + 0] = acc.x; lds[o + 1] = acc.y;
        lds[o + 2] = acc.z; lds[o + 3] = acc.w;
    }
    __syncthreads();
    if (t < P) {
        float s = lds[t] + lds[P + t] + lds[2 * P + t] + lds[3 * P + t] + lds[4 * P + t];
        partials[(size_t)blk * P + t] = s;
    }
}

// ---------------- kernel 2: threshold + bitmask-CC + bbox ----------------
// grid = 64 blocks x 256 threads. Phase A (all threads): sum partials, block
// max, threshold, one __ballot per wave -> 196-bit mask. Then thread 0 alone:
// register-resident flood-fill CC (8-connectivity), zero barriers.
__global__ __launch_bounds__(256) void bbox_kernel(const float* __restrict__ partials,
                                                   int* __restrict__ out) {
    const int b = blockIdx.x;
    const int t = threadIdx.x;

    __shared__ float redf[4];
    __shared__ unsigned long long ball[4];

    float a = -1e30f;
    if (t < P) {
        const float* pb = partials + (size_t)b * NCHUNK * P + t;
        a = 0.f;
        #pragma unroll
        for (int k = 0; k < NCHUNK; ++k) a += pb[k * P];
    }

    // block max: wave shuffle reduce + cross-wave LDS combine
    float mx = a;
    #pragma unroll
    for (int off = 32; off >= 1; off >>= 1) mx = fmaxf(mx, __shfl_xor(mx, off));
    if ((t & 63) == 0) redf[t >> 6] = mx;
    __syncthreads();
    const float maxv = fmaxf(fmaxf(redf[0], redf[1]), fmaxf(redf[2], redf[3]));

    const bool maskp = (t < P) && (a > maxv * 0.3f);
    const unsigned long long wb = __ballot(maskp);   // 64-bit on CDNA
    if ((t & 63) == 0) ball[t >> 6] = wb;
    __syncthreads();
    if (t != 0) return;

    // ---- thread-0 scalar phase: bitmask connected components ----
    const unsigned long long B0 = ball[0], B1 = ball[1], B2 = ball[2], B3 = ball[3];
    const unsigned long long B[4] = {B0, B1, B2, B3};
    unsigned rem[HH];
    #pragma unroll
    for (int r = 0; r < HH; ++r) {                   // unrolled -> static indices
        const int start = 14 * r, w = start >> 6, off = start & 63;
        unsigned long long v = B[w] >> off;
        if (off + 14 > 64) v |= B[w + 1] << (64 - off);
        rem[r] = (unsigned)v & 0x3FFFu;
    }

    unsigned bestRows[HH];
    #pragma unroll
    for (int r = 0; r < HH; ++r) bestRows[r] = 0;
    int bestA = 0;

    // extract components in raster order of their first pixel (= smallest
    // label id in the reference). Strict '>' keeps the first max -> matches
    // argmax tie-break (smallest label).
    for (;;) {
        int sr = -1;
        #pragma unroll
        for (int r = 0; r < HH; ++r) if (sr < 0 && rem[r]) sr = r;
        if (sr < 0) break;

        unsigned reach[HH];
        #pragma unroll
        for (int r = 0; r < HH; ++r) reach[r] = 0;
        reach[sr] = rem[sr] & (unsigned)(-(int)rem[sr]);   // lowest set bit

        // flood within rem: 8-conn = horizontal expand of self + vert neighbors
        for (;;) {
            unsigned h[HH];
            #pragma unroll
            for (int r = 0; r < HH; ++r)
                h[r] = reach[r] | (reach[r] << 1) | (reach[r] >> 1);
            unsigned diff = 0;
            #pragma unroll
            for (int r = 0; r < HH; ++r) {
                unsigned nv = h[r];
                if (r > 0)      nv |= h[r - 1];
                if (r < HH - 1) nv |= h[r + 1];
                nv &= rem[r];
                diff |= nv ^ reach[r];
                reach[r] = nv;
            }
            if (!diff) break;
        }

        int area = 0;
        #pragma unroll
        for (int r = 0; r < HH; ++r) area += __popc(reach[r]);
        if (area > bestA) {
            bestA = area;
            #pragma unroll
            for (int r = 0; r < HH; ++r) bestRows[r] = reach[r];
        }
        #pragma unroll
        for (int r = 0; r < HH; ++r) rem[r] &= ~reach[r];
    }

    int mnr, mxr, mnc, mxc;
    if (bestA == 0) {                                // empty-mask fallback
        mnr = 0; mxr = HH - 1; mnc = 0; mxc = WW - 1;
    } else {
        mnr = HH; mxr = -1;
        unsigned cols = 0;
        #pragma unroll
        for (int r = 0; r < HH; ++r) {
            if (bestRows[r]) {
                if (r < mnr) mnr = r;
                if (r > mxr) mxr = r;
                cols |= bestRows[r];
            }
        }
        mnc = __ffs(cols) - 1;
        mxc = 31 - __clz(cols);
    }
    out[b * 4 + 0] = max(mnr * 32 - 1, 0);
    out[b * 4 + 1] = max(mnc * 32 - 1, 0);
    out[b * 4 + 2] = (mxr + 1) * 32 - 1;
    out[b * 4 + 3] = (mxc + 1) * 32 - 1;
}

extern "C" void kernel_launch(void* const* d_in, const int* in_sizes, int n_in,
                              void* d_out, int out_size, void* d_ws, size_t ws_size,
                              hipStream_t stream) {
    const float* fms = (const float*)d_in[0];
    int* out = (int*)d_out;
    float* partials = (float*)d_ws;   // 64*NCHUNK*196 floats = 802,816 B

    chansum_kernel<<<dim3(64 * NCHUNK), dim3(256), 0, stream>>>(fms, partials);
    bbox_kernel<<<dim3(64), dim3(256), 0, stream>>>(partials, out);
}

// Round 10
// 22.679 us; speedup vs baseline: 2.0681x; 1.1704x over previous
//
#include <hip/hip_runtime.h>

#define HH 14
#define WW 14
#define P 196          // HH*WW
#define CTOT 2048
#define NCHUNK 16
#define CCHUNK 128     // CTOT/NCHUNK
#define Q4 49          // P/4 float4 per channel row

// ---------------- kernel 1: partial channel sums (R1/R6 exact) ----------------
// Measured ~15.3 us (R8 double-launch diagnostic) = 102.8 MB @ 6.7 TB/s,
// ~96% of the demonstrated fabric rate. At the floor — do not touch.
__global__ __launch_bounds__(256) void chansum_kernel(const float* __restrict__ fms,
                                                      float* __restrict__ partials) {
    const int blk = blockIdx.x;
    const int b = blk >> 4;       // /NCHUNK
    const int k = blk & 15;       // %NCHUNK
    const float4* __restrict__ base =
        (const float4*)(fms + ((size_t)b * CTOT + (size_t)k * CCHUNK) * P);

    __shared__ float lds[5 * P];
    const int t = threadIdx.x;

    if (t < 5 * Q4) {             // 245 active lanes
        const int q = t % Q4;     // float4 column within a channel row
        const int r = t / Q4;     // row-group 0..4
        float4 acc = {0.f, 0.f, 0.f, 0.f};
        #pragma unroll 4
        for (int c = r; c < CCHUNK; c += 5) {
            float4 v = base[c * Q4 + q];
            acc.x += v.x; acc.y += v.y; acc.z += v.z; acc.w += v.w;
        }
        const int o = r * P + q * 4;
        lds[o + 0] = acc.x; lds[o + 1] = acc.y;
        lds[o + 2] = acc.z; lds[o + 3] = acc.w;
    }
    __syncthreads();
    if (t < P) {
        float s = lds[t] + lds[P + t] + lds[2 * P + t] + lds[3 * P + t] + lds[4 * P + t];
        partials[(size_t)blk * P + t] = s;
    }
}

// ---------------- kernel 2: threshold + bitmask-CC + bbox ----------------
// grid = 64 blocks x 256 threads. Phase A: sum partials, block max, ballot.
// Then wave 0 only: all-full fast path, else lane-parallel flood fill
// (rows 0..13 one-per-lane, vertical neighbors via shfl).
__global__ __launch_bounds__(256) void bbox_kernel(const float* __restrict__ partials,
                                                   int* __restrict__ out) {
    const int b = blockIdx.x;
    const int t = threadIdx.x;

    __shared__ float redf[4];
    __shared__ unsigned long long ball[4];

    float a = -1e30f;
    if (t < P) {
        const float* pb = partials + (size_t)b * NCHUNK * P + t;
        a = 0.f;
        #pragma unroll
        for (int k = 0; k < NCHUNK; ++k) a += pb[k * P];
    }

    // block max: wave shuffle reduce + cross-wave LDS combine
    float mx = a;
    #pragma unroll
    for (int off = 32; off >= 1; off >>= 1) mx = fmaxf(mx, __shfl_xor(mx, off));
    if ((t & 63) == 0) redf[t >> 6] = mx;
    __syncthreads();
    const float maxv = fmaxf(fmaxf(redf[0], redf[1]), fmaxf(redf[2], redf[3]));

    const bool maskp = (t < P) && (a > maxv * 0.3f);
    const unsigned long long wb = __ballot(maskp);   // 64-bit on CDNA
    if ((t & 63) == 0) ball[t >> 6] = wb;
    __syncthreads();
    if (t >= 64) return;                             // wave 0 finishes

    const unsigned long long B0 = ball[0], B1 = ball[1], B2 = ball[2], B3 = ball[3];

    // ---- fast path: full mask == one component covering the grid ----
    if (B0 == ~0ull && B1 == ~0ull && B2 == ~0ull && (B3 & 0xFull) == 0xFull) {
        if (t == 0) {
            out[b * 4 + 0] = 0;
            out[b * 4 + 1] = 0;
            out[b * 4 + 2] = HH * 32 - 1;
            out[b * 4 + 3] = WW * 32 - 1;
        }
        return;
    }

    // ---- general path: lane-parallel flood fill (lane r owns row r) ----
    const int l = t;                                 // lane 0..63
    unsigned rem = 0;
    if (l < HH) {
        const int start = WW * l, w = start >> 6, off = start & 63;
        const unsigned long long Barr[4] = {B0, B1, B2, B3};
        unsigned long long v = Barr[w] >> off;
        if (off + WW > 64) v |= Barr[w + 1] << (64 - off);
        rem = (unsigned)v & 0x3FFFu;
    }

    unsigned bestRow = 0;
    int bestA = 0;

    // extract components in raster order of their first pixel (= smallest
    // label); strict '>' keeps the first max -> argmax smallest-label tie-break
    for (;;) {
        const unsigned long long rb = __ballot(rem != 0);
        if (rb == 0) break;
        const int sr = __ffsll(rb) - 1;              // first row with a pixel
        unsigned reach = (l == sr) ? (rem & (unsigned)(-(int)rem)) : 0u;

        for (;;) {
            const unsigned h = reach | (reach << 1) | (reach >> 1);
            const unsigned up = __shfl_up(h, 1);     // lane 0: own value (harmless)
            const unsigned dn = __shfl_down(h, 1);   // lane 13: lane14 h == 0
            const unsigned nv = (h | up | dn) & rem;
            const bool chg = (nv != reach);
            reach = nv;
            if (!__any(chg)) break;
        }

        int area = __popc(reach);
        #pragma unroll
        for (int off = 32; off >= 1; off >>= 1) area += __shfl_xor(area, off);
        if (area > bestA) { bestA = area; bestRow = reach; }
        rem &= ~reach;
    }

    int mnr, mxr, mnc, mxc;
    if (bestA == 0) {                                // empty-mask fallback
        mnr = 0; mxr = HH - 1; mnc = 0; mxc = WW - 1;
    } else {
        const unsigned long long rowb = __ballot(bestRow != 0);
        mnr = __ffsll(rowb) - 1;
        mxr = 63 - __clzll(rowb);
        unsigned cols = bestRow;
        #pragma unroll
        for (int off = 32; off >= 1; off >>= 1) cols |= __shfl_xor(cols, off);
        mnc = __ffs(cols) - 1;
        mxc = 31 - __clz(cols);
    }
    if (l == 0) {
        out[b * 4 + 0] = max(mnr * 32 - 1, 0);
        out[b * 4 + 1] = max(mnc * 32 - 1, 0);
        out[b * 4 + 2] = (mxr + 1) * 32 - 1;
        out[b * 4 + 3] = (mxc + 1) * 32 - 1;
    }
}

extern "C" void kernel_launch(void* const* d_in, const int* in_sizes, int n_in,
                              void* d_out, int out_size, void* d_ws, size_t ws_size,
                              hipStream_t stream) {
    const float* fms = (const float*)d_in[0];
    int* out = (int*)d_out;
    float* partials = (float*)d_ws;   // 64*NCHUNK*196 floats = 802,816 B

    chansum_kernel<<<dim3(64 * NCHUNK), dim3(256), 0, stream>>>(fms, partials);
    bbox_kernel<<<dim3(64), dim3(256), 0, stream>>>(partials, out);
}